// Round 1
// baseline (174.386 us; speedup 1.0000x reference)
//
#include <hip/hip_runtime.h>
#include <hip/hip_bf16.h>

#define NN 8192
#define DD 256
#define BM 128
#define BN 128
#define BK 32

typedef __bf16 bf16x8 __attribute__((ext_vector_type(8)));
typedef float f32x4 __attribute__((ext_vector_type(4)));

__device__ inline void gload_lds16(const void* g, void* l) {
  __builtin_amdgcn_global_load_lds(
      (const __attribute__((address_space(1))) void*)g,
      (__attribute__((address_space(3))) void*)l, 16, 0, 0);
}

// ---------------- prep: rnorm + bf16 hi/lo split ----------------
__global__ __launch_bounds__(256) void prep_kernel(
    const float* __restrict__ Z,
    __hip_bfloat16* __restrict__ Zhi,
    __hip_bfloat16* __restrict__ Zlo,
    float* __restrict__ rnorm) {
  const int gtid = blockIdx.x * 256 + threadIdx.x;
  const int row  = gtid >> 6;          // one wave per row
  const int lane = threadIdx.x & 63;
  if (row >= NN) return;

  const float4 v = reinterpret_cast<const float4*>(Z + (size_t)row * DD)[lane];
  float ss = v.x * v.x + v.y * v.y + v.z * v.z + v.w * v.w;
#pragma unroll
  for (int off = 32; off > 0; off >>= 1) ss += __shfl_xor(ss, off);
  if (lane == 0) rnorm[row] = 1.0f / fmaxf(sqrtf(ss), 1e-8f);

  float f[4] = {v.x, v.y, v.z, v.w};
  unsigned short hi[4], lo[4];
#pragma unroll
  for (int i = 0; i < 4; ++i) {
    __hip_bfloat16 h = __float2bfloat16(f[i]);
    float hf = __bfloat162float(h);
    __hip_bfloat16 l = __float2bfloat16(f[i] - hf);
    hi[i] = *reinterpret_cast<unsigned short*>(&h);
    lo[i] = *reinterpret_cast<unsigned short*>(&l);
  }
  ushort4 hv = make_ushort4(hi[0], hi[1], hi[2], hi[3]);
  ushort4 lv = make_ushort4(lo[0], lo[1], lo[2], lo[3]);
  reinterpret_cast<ushort4*>(Zhi + (size_t)row * DD)[lane] = hv;
  reinterpret_cast<ushort4*>(Zlo + (size_t)row * DD)[lane] = lv;
}

// ---------------- Gram GEMM + fused dual epilogue ----------------
__global__ __launch_bounds__(256, 2) void gram_kernel(
    const __hip_bfloat16* __restrict__ Zhi,
    const __hip_bfloat16* __restrict__ Zlo,
    const float* __restrict__ rnorm,
    const int* __restrict__ batch,
    float* __restrict__ outA,
    float* __restrict__ outS) {
  __shared__ __attribute__((aligned(16))) __hip_bfloat16 sAh[BM * BK];
  __shared__ __attribute__((aligned(16))) __hip_bfloat16 sAl[BM * BK];
  __shared__ __attribute__((aligned(16))) __hip_bfloat16 sBh[BN * BK];
  __shared__ __attribute__((aligned(16))) __hip_bfloat16 sBl[BN * BK];
  __shared__ float sRnA[BM];
  __shared__ float sRnB[BN];
  __shared__ int   sBtA[BM];
  __shared__ int   sBtB[BN];

  const int tid  = threadIdx.x;
  const int lane = tid & 63;
  const int wid  = tid >> 6;
  const int wr   = wid >> 1;   // 2x2 wave grid, each wave 64x64
  const int wc   = wid & 1;
  const int brow = blockIdx.y, bcol = blockIdx.x;
  const int row0 = brow * BM, col0 = bcol * BN;

  if (tid < 128) {
    sRnA[tid] = rnorm[row0 + tid];
    sBtA[tid] = batch[row0 + tid];
  } else {
    const int t = tid - 128;
    sRnB[t] = rnorm[col0 + t];
    sBtB[t] = batch[col0 + t];
  }

  f32x4 acc[4][4] = {};

  const int lr = lane >> 4;   // 0..3
  const int lc = lane & 15;   // 0..15

  for (int kt = 0; kt < DD / BK; ++kt) {
    const int k0 = kt * BK;
    // stage 4 tiles of 128x32 bf16; 2 chunks of 16B per thread per tile
#pragma unroll
    for (int c = 0; c < 2; ++c) {
      const int idx = c * 256 + tid;          // [0,512): 16B chunk index
      const int r = idx >> 2;                 // row in tile (4 chunks/row)
      const int ch = idx & 3;                 // which 8-col chunk
      const int base = (c * 256 + wid * 64) * 16;  // wave-uniform LDS byte base
      const size_t goffA = (size_t)(row0 + r) * DD + k0 + ch * 8;
      const size_t goffB = (size_t)(col0 + r) * DD + k0 + ch * 8;
      gload_lds16(Zhi + goffA, (char*)sAh + base);
      gload_lds16(Zlo + goffA, (char*)sAl + base);
      gload_lds16(Zhi + goffB, (char*)sBh + base);
      gload_lds16(Zlo + goffB, (char*)sBl + base);
    }
    __syncthreads();   // drains vmcnt before any wave reads LDS

    bf16x8 ah[4], al[4], bh[4], bl[4];
#pragma unroll
    for (int m = 0; m < 4; ++m) {
      const int off = (wr * 64 + m * 16 + lc) * BK + lr * 8;
      ah[m] = *reinterpret_cast<const bf16x8*>(&sAh[off]);
      al[m] = *reinterpret_cast<const bf16x8*>(&sAl[off]);
    }
#pragma unroll
    for (int n = 0; n < 4; ++n) {
      const int off = (wc * 64 + n * 16 + lc) * BK + lr * 8;
      bh[n] = *reinterpret_cast<const bf16x8*>(&sBh[off]);
      bl[n] = *reinterpret_cast<const bf16x8*>(&sBl[off]);
    }
#pragma unroll
    for (int m = 0; m < 4; ++m) {
#pragma unroll
      for (int n = 0; n < 4; ++n) {
        acc[m][n] = __builtin_amdgcn_mfma_f32_16x16x32_bf16(ah[m], bh[n], acc[m][n], 0, 0, 0);
        acc[m][n] = __builtin_amdgcn_mfma_f32_16x16x32_bf16(ah[m], bl[n], acc[m][n], 0, 0, 0);
        acc[m][n] = __builtin_amdgcn_mfma_f32_16x16x32_bf16(al[m], bh[n], acc[m][n], 0, 0, 0);
      }
    }
    __syncthreads();
  }

  // fused epilogue: A = sigmoid(g); S = same-batch ? g*rn_i*rn_j : 0
#pragma unroll
  for (int m = 0; m < 4; ++m) {
#pragma unroll
    for (int n = 0; n < 4; ++n) {
      const int coll = wc * 64 + n * 16 + lc;
      const int colg = col0 + coll;
      const float rb = sRnB[coll];
      const int   bb = sBtB[coll];
#pragma unroll
      for (int j = 0; j < 4; ++j) {
        const int rowl = wr * 64 + m * 16 + lr * 4 + j;
        const int rowg = row0 + rowl;
        const float g = acc[m][n][j];
        const float a = 1.0f / (1.0f + __expf(-g));
        const float s = (sBtA[rowl] == bb) ? g * sRnA[rowl] * rb : 0.0f;
        const size_t o = (size_t)rowg * NN + colg;
        outA[o] = a;
        outS[o] = s;
      }
    }
  }
}

extern "C" void kernel_launch(void* const* d_in, const int* in_sizes, int n_in,
                              void* d_out, int out_size, void* d_ws, size_t ws_size,
                              hipStream_t stream) {
  const float* Z     = (const float*)d_in[0];
  const int*   batch = (const int*)d_in[1];
  float* out = (float*)d_out;

  __hip_bfloat16* Zhi = (__hip_bfloat16*)d_ws;
  __hip_bfloat16* Zlo = Zhi + (size_t)NN * DD;
  float* rnorm = (float*)(Zlo + (size_t)NN * DD);

  prep_kernel<<<NN / 4, 256, 0, stream>>>(Z, Zhi, Zlo, rnorm);

  dim3 grid(NN / BN, NN / BM);
  gram_kernel<<<grid, 256, 0, stream>>>(Zhi, Zlo, rnorm, batch, out,
                                        out + (size_t)NN * NN);
}

// Round 2
// 173.477 us; speedup vs baseline: 1.0052x; 1.0052x over previous
//
#include <hip/hip_runtime.h>
#include <hip/hip_bf16.h>

#define NN 8192
#define DD 256
#define BM 128
#define BN 128
#define BK 32

typedef __bf16 bf16x8 __attribute__((ext_vector_type(8)));
typedef float f32x4 __attribute__((ext_vector_type(4)));

__device__ inline void gload_lds16(const void* g, void* l) {
  __builtin_amdgcn_global_load_lds(
      (const __attribute__((address_space(1))) void*)g,
      (__attribute__((address_space(3))) void*)l, 16, 0, 0);
}

// ---------------- prep: rnorm + bf16 hi/lo split ----------------
__global__ __launch_bounds__(256) void prep_kernel(
    const float* __restrict__ Z,
    __hip_bfloat16* __restrict__ Zhi,
    __hip_bfloat16* __restrict__ Zlo,
    float* __restrict__ rnorm) {
  const int gtid = blockIdx.x * 256 + threadIdx.x;
  const int row  = gtid >> 6;          // one wave per row
  const int lane = threadIdx.x & 63;
  if (row >= NN) return;

  const float4 v = reinterpret_cast<const float4*>(Z + (size_t)row * DD)[lane];
  float ss = v.x * v.x + v.y * v.y + v.z * v.z + v.w * v.w;
#pragma unroll
  for (int off = 32; off > 0; off >>= 1) ss += __shfl_xor(ss, off);
  if (lane == 0) rnorm[row] = 1.0f / fmaxf(sqrtf(ss), 1e-8f);

  float f[4] = {v.x, v.y, v.z, v.w};
  unsigned short hi[4], lo[4];
#pragma unroll
  for (int i = 0; i < 4; ++i) {
    __hip_bfloat16 h = __float2bfloat16(f[i]);
    float hf = __bfloat162float(h);
    __hip_bfloat16 l = __float2bfloat16(f[i] - hf);
    hi[i] = *reinterpret_cast<unsigned short*>(&h);
    lo[i] = *reinterpret_cast<unsigned short*>(&l);
  }
  ushort4 hv = make_ushort4(hi[0], hi[1], hi[2], hi[3]);
  ushort4 lv = make_ushort4(lo[0], lo[1], lo[2], lo[3]);
  reinterpret_cast<ushort4*>(Zhi + (size_t)row * DD)[lane] = hv;
  reinterpret_cast<ushort4*>(Zlo + (size_t)row * DD)[lane] = lv;
}

// LDS: K-loop staging tiles union'd with the f32 transpose buffer
struct __attribute__((aligned(16))) SharedT {
  union {
    struct {
      __hip_bfloat16 Ah[BM * BK];
      __hip_bfloat16 Al[BM * BK];
      __hip_bfloat16 Bh[BN * BK];
      __hip_bfloat16 Bl[BN * BK];
    } t;
    float tbuf[BM][BN + 1];   // pad+1: transposed read conflict-free
  };
};

// ---------------- upper-tri Gram GEMM + dual epilogue (direct + mirrored) ----
__global__ __launch_bounds__(256, 2) void gram_kernel(
    const __hip_bfloat16* __restrict__ Zhi,
    const __hip_bfloat16* __restrict__ Zlo,
    const float* __restrict__ rnorm,
    const int* __restrict__ batch,
    float* __restrict__ outA,
    float* __restrict__ outS) {
  __shared__ SharedT sh;
  __shared__ float sRnA[BM];
  __shared__ float sRnB[BN];
  __shared__ int   sBtA[BM];
  __shared__ int   sBtB[BN];

  const int tid  = threadIdx.x;
  const int lane = tid & 63;
  const int wid  = tid >> 6;
  const int wr   = wid >> 1;   // 2x2 wave grid, each wave 64x64
  const int wc   = wid & 1;

  // triangular decode: idx -> (brow <= bcol)
  const int idx = blockIdx.x;
  int bcol = (int)((sqrtf(8.0f * (float)idx + 1.0f) - 1.0f) * 0.5f);
  while ((bcol + 1) * (bcol + 2) / 2 <= idx) ++bcol;
  while (bcol * (bcol + 1) / 2 > idx) --bcol;
  const int brow = idx - bcol * (bcol + 1) / 2;
  const int row0 = brow * BM, col0 = bcol * BN;

  if (tid < 128) {
    sRnA[tid] = rnorm[row0 + tid];
    sBtA[tid] = batch[row0 + tid];
  } else {
    const int t = tid - 128;
    sRnB[t] = rnorm[col0 + t];
    sBtB[t] = batch[col0 + t];
  }

  f32x4 acc[4][4] = {};

  const int lr = lane >> 4;   // 0..3  (k-chunk)
  const int lc = lane & 15;   // 0..15 (row within fragment)

  for (int kt = 0; kt < DD / BK; ++kt) {
    const int k0 = kt * BK;
    // stage 4 tiles of 128x32 bf16, XOR-swizzled on the GLOBAL side
    // (LDS dest linear; involution ch ^= (r>>1)&3 applied again on read)
#pragma unroll
    for (int c = 0; c < 2; ++c) {
      const int ci  = c * 256 + tid;            // 16B-chunk index [0,512)
      const int r   = ci >> 2;                  // tile-local row
      const int ch  = ci & 3;
      const int chg = ch ^ ((r >> 1) & 3);      // swizzled source chunk
      const int base = (c * 256 + wid * 64) * 16;  // wave-uniform LDS byte base
      const size_t ga = (size_t)(row0 + r) * DD + k0 + chg * 8;
      const size_t gb = (size_t)(col0 + r) * DD + k0 + chg * 8;
      gload_lds16(Zhi + ga, (char*)sh.t.Ah + base);
      gload_lds16(Zlo + ga, (char*)sh.t.Al + base);
      gload_lds16(Zhi + gb, (char*)sh.t.Bh + base);
      gload_lds16(Zlo + gb, (char*)sh.t.Bl + base);
    }
    __syncthreads();   // drains vmcnt before any wave reads LDS

    bf16x8 ah[4], al[4], bh[4], bl[4];
#pragma unroll
    for (int m = 0; m < 4; ++m) {
      const int rA = wr * 64 + m * 16 + lc;
      const int off = rA * BK + ((lr ^ ((rA >> 1) & 3)) << 3);
      ah[m] = *reinterpret_cast<const bf16x8*>(&sh.t.Ah[off]);
      al[m] = *reinterpret_cast<const bf16x8*>(&sh.t.Al[off]);
    }
#pragma unroll
    for (int n = 0; n < 4; ++n) {
      const int rB = wc * 64 + n * 16 + lc;
      const int off = rB * BK + ((lr ^ ((rB >> 1) & 3)) << 3);
      bh[n] = *reinterpret_cast<const bf16x8*>(&sh.t.Bh[off]);
      bl[n] = *reinterpret_cast<const bf16x8*>(&sh.t.Bl[off]);
    }
#pragma unroll
    for (int m = 0; m < 4; ++m) {
#pragma unroll
      for (int n = 0; n < 4; ++n) {
        acc[m][n] = __builtin_amdgcn_mfma_f32_16x16x32_bf16(ah[m], bh[n], acc[m][n], 0, 0, 0);
        acc[m][n] = __builtin_amdgcn_mfma_f32_16x16x32_bf16(ah[m], bl[n], acc[m][n], 0, 0, 0);
        acc[m][n] = __builtin_amdgcn_mfma_f32_16x16x32_bf16(al[m], bh[n], acc[m][n], 0, 0, 0);
      }
    }
    __syncthreads();
  }

  const bool mirror = (brow != bcol);

  // stage raw g into tbuf for the mirrored write (tiles are dead now)
  if (mirror) {
#pragma unroll
    for (int m = 0; m < 4; ++m)
#pragma unroll
      for (int n = 0; n < 4; ++n)
#pragma unroll
        for (int j = 0; j < 4; ++j) {
          const int rowl = wr * 64 + m * 16 + lr * 4 + j;
          const int coll = wc * 64 + n * 16 + lc;
          sh.tbuf[rowl][coll] = acc[m][n][j];
        }
  }

  // phase A: direct tile write (coalesced from acc layout)
#pragma unroll
  for (int m = 0; m < 4; ++m) {
#pragma unroll
    for (int n = 0; n < 4; ++n) {
      const int coll = wc * 64 + n * 16 + lc;
      const int colg = col0 + coll;
      const float rb = sRnB[coll];
      const int   bb = sBtB[coll];
#pragma unroll
      for (int j = 0; j < 4; ++j) {
        const int rowl = wr * 64 + m * 16 + lr * 4 + j;
        const int rowg = row0 + rowl;
        const float g = acc[m][n][j];
        const float a = 1.0f / (1.0f + __expf(-g));
        const float s = (sBtA[rowl] == bb) ? g * sRnA[rowl] * rb : 0.0f;
        const size_t o = (size_t)rowg * NN + colg;
        outA[o] = a;
        outS[o] = s;
      }
    }
  }

  // phase B: mirrored tile write via LDS transpose (conflict-free reads,
  // 512B-coalesced stores)
  if (mirror) {
    __syncthreads();
#pragma unroll 8
    for (int i = 0; i < (BM * BN) / 256; ++i) {
      const int e  = i * 256 + tid;
      const int rt = e >> 7;       // transposed row  = original col
      const int ct = e & 127;      // transposed col  = original row
      const float g = sh.tbuf[ct][rt];
      const float a = 1.0f / (1.0f + __expf(-g));
      const float s = (sBtB[rt] == sBtA[ct]) ? g * sRnB[rt] * sRnA[ct] : 0.0f;
      const size_t o = (size_t)(col0 + rt) * NN + (row0 + ct);
      outA[o] = a;
      outS[o] = s;
    }
  }
}

extern "C" void kernel_launch(void* const* d_in, const int* in_sizes, int n_in,
                              void* d_out, int out_size, void* d_ws, size_t ws_size,
                              hipStream_t stream) {
  const float* Z     = (const float*)d_in[0];
  const int*   batch = (const int*)d_in[1];
  float* out = (float*)d_out;

  __hip_bfloat16* Zhi = (__hip_bfloat16*)d_ws;
  __hip_bfloat16* Zlo = Zhi + (size_t)NN * DD;
  float* rnorm = (float*)(Zlo + (size_t)NN * DD);

  prep_kernel<<<NN / 4, 256, 0, stream>>>(Z, Zhi, Zlo, rnorm);

  const int nb = NN / BM;                 // 64
  const int nblocks = nb * (nb + 1) / 2;  // 2080
  gram_kernel<<<dim3(nblocks), 256, 0, stream>>>(Zhi, Zlo, rnorm, batch, out,
                                                 out + (size_t)NN * NN);
}